// Round 1
// 412.244 us; speedup vs baseline: 1.7633x; 1.7633x over previous
//
#include <hip/hip_runtime.h>
#include <cstddef>

// Problem dims
#define CI_  64
#define CO_  256
#define DD_  31
#define HH_  96
#define WW_  96
#define HW_  (HH_*WW_)      // 9216
#define DHW_ (DD_*HW_)      // 285696
#define EPSV 1e-5f

// Padded channels-last fp16 input: xt[cig8][pd33][ph98][pw98][ci8]
#define PD_   33
#define PH_   98
#define PW_   98
#define PHW_  9604          // 98*98
#define PDHW_ 316932        // 33*9604

// Conv tile: M=128 (8h x 16w) x N=256 (4 waves x 64co), one d per block.
// LDS halo: [dd3][row10][cig8][col18][ci8] halves — linear in task order.
#define S_COL 8
#define S_CIG 144           // 18*8
#define S_ROW 1152          // 8*144
#define S_DD  11520         // 10*1152
#define NTASK 4320          // 3*10*8*18 real 16B tasks
#define NTASKP 4352         // padded to 17*256
#define XH_N  (NTASKP*8)    // 34816 halves = 69632 B

#define HTI_  12
#define WTI_  6
#define NTILE 72            // 12 hti * 6 wti per d-plane
#define NBLK  (NTILE*DD_)   // 2232 conv blocks (= 8*279, XCD-exact)
#define GSP   128           // spatial elems per block gate region per co

typedef _Float16 half8   __attribute__((ext_vector_type(8)));
typedef _Float16 half4v  __attribute__((ext_vector_type(4)));
typedef _Float16 half2v  __attribute__((ext_vector_type(2)));
typedef float    float4v __attribute__((ext_vector_type(4)));

__device__ __forceinline__ void gl_lds16(const _Float16* g, _Float16* l) {
  __builtin_amdgcn_global_load_lds(
      (const __attribute__((address_space(1))) unsigned int*)(g),
      (__attribute__((address_space(3))) unsigned int*)(l), 16, 0, 0);
}

// -------- weight repack: w[co][ci][27] fp32 -> wr2[t][kc][cog][quad][lw][ci8] fp16
// Conv reads B frag at ((t*2+kc)*16 + cog)*512 + lane*8 -> fully dense 1KB/wave.
__global__ __launch_bounds__(256) void repack_w_k(const float* __restrict__ w,
                                                  _Float16* __restrict__ wr2) {
  int idx = blockIdx.x * 256 + threadIdx.x;   // 27*2*16*4*16 = 55296
  if (idx >= 55296) return;
  int lw   = idx & 15;
  int quad = (idx >> 4) & 3;
  int cog  = (idx >> 6) & 15;
  int tkc  = idx >> 10;          // t*2+kc
  int kc   = tkc & 1;
  int t    = tkc >> 1;
  int co   = cog * 16 + lw;
  int cib  = kc * 32 + quad * 8;
  half8 v;
#pragma unroll
  for (int s = 0; s < 8; s++)
    v[s] = (_Float16)w[(size_t)co * 1728 + (size_t)(cib + s) * 27 + t];
  *(half8*)(wr2 + (size_t)idx * 8) = v;
}

// -------- x transpose: fp32 NCDHW -> zero-padded fp16 channels-last ----------
__global__ __launch_bounds__(256) void transpose_x_k(const float* __restrict__ x,
                                                     _Float16* __restrict__ xt) {
  int p = blockIdx.x * 256 + threadIdx.x;
  if (p >= PDHW_) return;
  int pd  = p / PHW_;
  int rem = p - pd * PHW_;
  int ph  = rem / PW_;
  int pw  = rem - ph * PW_;
  bool in = (pd >= 1) & (pd <= DD_) & (ph >= 1) & (ph <= HH_) & (pw >= 1) & (pw <= WW_);
  if (in) {
    const float* xp = x + (size_t)(pd - 1) * HW_ + (size_t)(ph - 1) * WW_ + (pw - 1);
#pragma unroll
    for (int cig = 0; cig < 8; cig++) {
      half8 v;
#pragma unroll
      for (int s = 0; s < 8; s++)
        v[s] = (_Float16)xp[(size_t)(cig * 8 + s) * DHW_];
      *(half8*)(xt + ((size_t)cig * PDHW_ + p) * 8) = v;
    }
  } else {
    half8 z = (half8)(_Float16)0.f;
#pragma unroll
    for (int cig = 0; cig < 8; cig++)
      *(half8*)(xt + ((size_t)cig * PDHW_ + p) * 8) = z;
  }
}

// -------- conv3d (implicit GEMM, f16 MFMA) + BN + act -> block-private gates ----
// grid: 2232 blocks (XCD-chunk swizzled). block 256 = 4 waves (co groups).
// Single staging phase (64 ci, global_load_lds direct), ONE barrier, then a
// barrier-free K loop: 2 kc x 27 taps x 8 m x 4 j MFMAs per wave.
__global__ __launch_bounds__(256, 2) void conv_mfma_k(
    const _Float16* __restrict__ xt, const _Float16* __restrict__ wr2,
    const float* __restrict__ gamma, const float* __restrict__ beta,
    const float* __restrict__ mean, const float* __restrict__ var,
    _Float16* __restrict__ gates)
{
  __shared__ _Float16 xh[XH_N];

  // XCD-chunked swizzle: 2232 = 8 * 279 exactly (bijective)
  const int bid  = blockIdx.x;
  const int flat = (bid & 7) * 279 + (bid >> 3);
  const int d    = flat / NTILE;
  const int bx   = flat - d * NTILE;
  const int wti  = bx % 6;
  const int hti  = bx / 6;
  const int h0   = hti * 8, w0 = wti * 16;

  const int tid  = threadIdx.x;
  const int lane = tid & 63;
  const int wave = __builtin_amdgcn_readfirstlane(tid >> 6);
  const int lw   = lane & 15;        // A: m(spatial w)  B: n(co)
  const int quad = lane >> 4;        // k-group (8 ci)

  // ---- stage halo: 4352 16B tasks, direct global->LDS DMA, all in-bounds ----
#pragma unroll 1
  for (int it = 0; it < 17; ++it) {
    const int wb   = it * 256 + wave * 64;     // wave-uniform LDS base task
    const int task = wb + lane;
    const int tt   = task < NTASK ? task : (NTASK - 1);  // spare lanes dup-load
    int col = tt % 18;
    int rc  = tt / 18;
    int cig = rc & 7;
    int dr  = rc >> 3;
    int dd  = dr / 10;
    int row = dr - dd * 10;
    const _Float16* g = xt + (((size_t)cig * PDHW_ + (size_t)(d + dd) * PHW_ +
                               (size_t)(h0 + row) * PW_ + (w0 + col)) << 3);
    gl_lds16(g, xh + (size_t)wb * 8);
  }

  float4v acc[8][4];
#pragma unroll
  for (int m = 0; m < 8; m++)
#pragma unroll
    for (int j = 0; j < 4; j++) acc[m][j] = (float4v)0.f;

  __syncthreads();   // vmcnt(0) drain of global_load_lds + barrier

  // ---- K loop: no barriers; waves free-run to hide B-load latency ----
#pragma unroll 1
  for (int t9 = 0; t9 < 9; ++t9) {   // kd*3+kh
    const int kd = t9 / 3;
    const int kh = t9 - kd * 3;
#pragma unroll
    for (int kc = 0; kc < 2; ++kc) {
#pragma unroll
      for (int kw = 0; kw < 3; ++kw) {
        const int t = t9 * 3 + kw;
        const _Float16* bp = wr2 + (((size_t)((t * 2 + kc) * 16 + wave * 4)) << 9) + (lane << 3);
        half8 bf[4];
#pragma unroll
        for (int j = 0; j < 4; ++j) bf[j] = *(const half8*)(bp + ((size_t)j << 9));
        const int ab = kd * S_DD + kh * S_ROW + (kc * 4 + quad) * S_CIG + (lw + kw) * S_COL;
#pragma unroll
        for (int m = 0; m < 8; ++m) {
          half8 af = *(const half8*)(xh + ab + m * S_ROW);
#pragma unroll
          for (int j = 0; j < 4; ++j)
            acc[m][j] = __builtin_amdgcn_mfma_f32_16x16x32_f16(af, bf[j], acc[m][j], 0, 0, 0);
        }
      }
    }
  }

  // ---- epilogue: BN + activation, block-private gate region ----
  // gates[((d*72+bx)*256 + co)*128 + sp], sp = h_local*16 + w_local
  _Float16* gb = gates + ((size_t)(d * NTILE + bx) * 256) * GSP;
  const bool istanh = (wave == 0) || (wave == 3);
#pragma unroll
  for (int j = 0; j < 4; j++) {
    const int co = wave * 64 + j * 16 + lw;
    const float s  = gamma[co] * rsqrtf(var[co] + EPSV);
    const float bb = fmaf(-mean[co], s, beta[co]);
#pragma unroll
    for (int m = 0; m < 8; m++) {
      half4v hv;
#pragma unroll
      for (int reg = 0; reg < 4; reg++) {
        float v = fmaf(acc[m][j][reg], s, bb);
        float a;
        if (istanh) {
          float tt = __expf(-2.f * fabsf(v));
          float r  = (1.f - tt) * __builtin_amdgcn_rcpf(1.f + tt);
          a = copysignf(r, v);
        } else {
          a = __builtin_amdgcn_rcpf(1.f + __expf(-v));
        }
        hv[reg] = (_Float16)a;
      }
      // D row index = quad*4+reg -> w_local; m = h_local
      *(half4v*)(gb + (size_t)co * GSP + m * 16 + quad * 4) = hv;
    }
  }
}

// -------- SRU recurrence over d; thread per (c, bx, 2-wide sp); pipelined ----
__global__ __launch_bounds__(256) void recurrence_k(const _Float16* __restrict__ gates,
                                                    float* __restrict__ out) {
  const int idx = blockIdx.x * 256 + threadIdx.x;   // 64*72*64 = 294912
  const int ml2 = idx & 63;
  const int t2  = idx >> 6;          // c*72 + bx
  const int c   = t2 / NTILE;
  const int bx  = t2 - c * NTILE;
  const int hti = bx / 6, wti = bx - hti * 6;
  const int sp  = ml2 * 2;
  const int h   = hti * 8 + (sp >> 4);
  const int w   = wti * 16 + (sp & 15);

  const size_t DSTR = (size_t)NTILE * 256 * GSP;    // per-d gate stride
  const _Float16* g0 = gates + (size_t)bx * 256 * GSP + sp;
  float* op = out + (size_t)c * DHW_ + (size_t)h * WW_ + w;

#define LD(dv, gate) (*(const half2v*)(g0 + (size_t)(dv) * DSTR + (size_t)(c + ((gate) << 6)) * GSP))

  // d = 0 (peeled): C = 1 - f
  half2v cf = LD(0, 1), cr = LD(0, 2), cx = LD(0, 3);
  half2v nwx = LD(1, 0), nf = LD(1, 1), nr = LD(1, 2), nx = LD(1, 3);
  float C0 = 1.f - (float)cf[0];
  float C1 = 1.f - (float)cf[1];
  {
    float r0 = (float)cr[0], x0 = (float)cx[0];
    float r1 = (float)cr[1], x1 = (float)cx[1];
    float2 st = {fmaf(r0, C0 - x0, x0), fmaf(r1, C1 - x1, x1)};
    *(float2*)op = st;
  }
#pragma unroll 1
  for (int d = 1; d < DD_; d++) {
    half2v cwx = nwx; cf = nf; cr = nr; cx = nx;
    if (d < DD_ - 1) {                 // prefetch d+1 while computing d
      nwx = LD(d + 1, 0); nf = LD(d + 1, 1);
      nr  = LD(d + 1, 2); nx = LD(d + 1, 3);
    }
    float wx0 = (float)cwx[0], f0 = (float)cf[0], r0 = (float)cr[0], x0 = (float)cx[0];
    float wx1 = (float)cwx[1], f1 = (float)cf[1], r1 = (float)cr[1], x1 = (float)cx[1];
    C0 = fmaf(f0, C0 - wx0, wx0);
    C1 = fmaf(f1, C1 - wx1, wx1);
    float2 st = {fmaf(r0, C0 - x0, x0), fmaf(r1, C1 - x1, x1)};
    *(float2*)(op + (size_t)d * HW_) = st;
  }
#undef LD
}

extern "C" void kernel_launch(void* const* d_in, const int* in_sizes, int n_in,
                              void* d_out, int out_size, void* d_ws, size_t ws_size,
                              hipStream_t stream) {
  const float* x     = (const float*)d_in[0];
  const float* w     = (const float*)d_in[1];
  const float* gamma = (const float*)d_in[2];
  const float* beta  = (const float*)d_in[3];
  const float* mean  = (const float*)d_in[4];
  const float* var   = (const float*)d_in[5];
  float* out = (float*)d_out;

  // ws: [wr2: 884736 B][xt: 8*316932*8*2 = 40567296 B][gates: 31*72*256*128*2 B]
  _Float16* wr2   = (_Float16*)d_ws;
  _Float16* xt    = (_Float16*)((char*)d_ws + 884736);
  _Float16* gates = (_Float16*)((char*)d_ws + 884736 + 40567296);

  repack_w_k<<<216, 256, 0, stream>>>(w, wr2);
  transpose_x_k<<<(PDHW_ + 255) / 256, 256, 0, stream>>>(x, xt);
  conv_mfma_k<<<NBLK, 256, 0, stream>>>(xt, wr2, gamma, beta, mean, var, gates);
  recurrence_k<<<(64 * NTILE * 64) / 256, 256, 0, stream>>>(gates, out);
}